// Round 1
// baseline (305.322 us; speedup 1.0000x reference)
//
#include <hip/hip_runtime.h>
#include <math.h>

// Mamba-2D (SS2D) for B=2, C=64, H=W=64, d_inner=128, d_state=16, dt_rank=4.
// Pair index p = dir*2 + b  (8 pairs). Sequence length L=4096, chunked scan 64x64.

__device__ __forceinline__ float sigmoidf_(float x){ return 1.0f/(1.0f+__expf(-x)); }

// ---------------- LayerNorm over channels (C=64) ----------------
__global__ __launch_bounds__(256) void k_ln(const float* __restrict__ x,
    const float* __restrict__ lw, const float* __restrict__ lb, float* __restrict__ xn) {
  int tid = threadIdx.x;
  int lane = tid & 63;                    // channel
  int pos = blockIdx.x*4 + (tid>>6);      // 0..8191 = b*4096 + hw
  int b = pos >> 12, hw = pos & 4095;
  float v = x[((long)(b*64 + lane))*4096 + hw];
  float s = v;
  for (int m = 32; m; m >>= 1) s += __shfl_xor(s, m);
  float mu = s * (1.0f/64.0f);
  float dv = (v-mu)*(v-mu);
  for (int m = 32; m; m >>= 1) dv += __shfl_xor(dv, m);
  float rs = rsqrtf(dv*(1.0f/64.0f) + 1e-5f);
  xn[(long)pos*64 + lane] = (v-mu)*rs*lw[lane] + lb[lane];
}

// ---------------- Build 4 direction-permuted sequences ----------------
__global__ __launch_bounds__(256) void k_xseq(const float* __restrict__ xn, float* __restrict__ xseq) {
  int gid = blockIdx.x*256 + threadIdx.x;   // 8*4096*64 = 2097152
  int c = gid & 63;
  int t = (gid >> 6) & 4095;
  int p = gid >> 18;
  int b = p & 1, dir = p >> 1;
  int l;
  if (dir == 0) l = t;
  else if (dir == 1) l = 4095 - t;
  else {
    int tt = (dir == 2) ? t : 4095 - t;
    l = ((tt & 63) << 6) | (tt >> 6);       // t = w*64+h  ->  l = h*64+w
  }
  xseq[gid] = xn[((long)(b*4096 + l))*64 + c];
}

// ---------------- Generic f32 GEMM: C[m,n] = sum_k A[m,k]*B[n,k] ----------------
// Weights B are per-direction: Bp = Bw + (pair>>1)*bStr.
__global__ __launch_bounds__(256) void k_gemm(const float* __restrict__ A, const float* __restrict__ Bw,
    float* __restrict__ C, int M, int N, int K, long aStr, long bStr, long cStr) {
  __shared__ float Ast[64][68];
  __shared__ float Bst[64][68];
  int pair = blockIdx.z;
  const float* Ap = A + (long)pair*aStr;
  const float* Bp = Bw + (long)(pair>>1)*bStr;
  float* Cp = C + (long)pair*cStr;
  int tid = threadIdx.x;
  int tx = tid & 15, ty = tid >> 4;
  int m0 = blockIdx.x*64, n0 = blockIdx.y*64;
  int kk4 = tid & 15, rr = tid >> 4;
  float acc[4][4] = {};
  for (int ko = 0; ko < K; ko += 64) {
    for (int pass = 0; pass < 4; ++pass) {
      int r = pass*16 + rr;
      float4 av = *(const float4*)(Ap + (long)(m0+r)*K + ko + kk4*4);
      Ast[kk4*4+0][r]=av.x; Ast[kk4*4+1][r]=av.y; Ast[kk4*4+2][r]=av.z; Ast[kk4*4+3][r]=av.w;
      int j = n0 + r;
      float4 bv = make_float4(0.f,0.f,0.f,0.f);
      if (j < N) bv = *(const float4*)(Bp + (long)j*K + ko + kk4*4);
      Bst[kk4*4+0][r]=bv.x; Bst[kk4*4+1][r]=bv.y; Bst[kk4*4+2][r]=bv.z; Bst[kk4*4+3][r]=bv.w;
    }
    __syncthreads();
    #pragma unroll 8
    for (int kk = 0; kk < 64; ++kk) {
      float4 a = *(const float4*)(&Ast[kk][ty*4]);
      float4 b = *(const float4*)(&Bst[kk][tx*4]);
      acc[0][0] += a.x*b.x; acc[0][1] += a.x*b.y; acc[0][2] += a.x*b.z; acc[0][3] += a.x*b.w;
      acc[1][0] += a.y*b.x; acc[1][1] += a.y*b.y; acc[1][2] += a.y*b.z; acc[1][3] += a.y*b.w;
      acc[2][0] += a.z*b.x; acc[2][1] += a.z*b.y; acc[2][2] += a.z*b.z; acc[2][3] += a.z*b.w;
      acc[3][0] += a.w*b.x; acc[3][1] += a.w*b.y; acc[3][2] += a.w*b.z; acc[3][3] += a.w*b.w;
    }
    __syncthreads();
  }
  for (int i = 0; i < 4; ++i)
    for (int j = 0; j < 4; ++j) {
      int m = m0 + ty*4 + i, n = n0 + tx*4 + j;
      if (n < N) Cp[(long)m*N + n] = acc[i][j];
    }
}

// ---------------- Causal depthwise conv(3) + bias + silu ----------------
__global__ __launch_bounds__(256) void k_conv(const float* __restrict__ xz, const float* __restrict__ cw,
    const float* __restrict__ cb, float* __restrict__ u) {
  int gid = blockIdx.x*256 + threadIdx.x;   // 8*4096*128
  int d = gid & 127;
  int t = (gid >> 7) & 4095;
  int p = gid >> 19;
  int dir = p >> 1;
  const float* base = xz + ((long)p*4096)*256 + d;   // xp = cols 0..127
  float x2 = base[(long)t*256];
  float x1 = (t >= 1) ? base[(long)(t-1)*256] : 0.f;
  float x0 = (t >= 2) ? base[(long)(t-2)*256] : 0.f;
  const float* w = cw + (dir*128 + d)*3;
  float a = x0*w[0] + x1*w[1] + x2*w[2] + cb[dir*128 + d];
  u[gid] = a * sigmoidf_(a);
}

// ---------------- dt = softplus(dt_raw @ W_dt^T + b_dt) ----------------
__global__ __launch_bounds__(256) void k_dt(const float* __restrict__ dbl, const float* __restrict__ wdt,
    const float* __restrict__ bdt, float* __restrict__ dt) {
  int gid = blockIdx.x*256 + threadIdx.x;   // 8*4096*128
  int d = gid & 127;
  int t = (gid >> 7) & 4095;
  int p = gid >> 19;
  int dir = p >> 1;
  const float* r = dbl + ((long)p*4096 + t)*36;
  float4 w = *(const float4*)(wdt + ((dir*128 + d) << 2));
  float lin = r[0]*w.x + r[1]*w.y + r[2]*w.z + r[3]*w.w + bdt[dir*128 + d];
  float sp = (lin > 20.f) ? lin : log1pf(__expf(lin));
  dt[gid] = sp;
}

// ---------------- Scan phase 1: per-chunk particular solution + sum(dt) ----------------
__global__ __launch_bounds__(256) void k_scan1(const float* __restrict__ dt, const float* __restrict__ u,
    const float* __restrict__ dbl, const float* __restrict__ alog,
    float* __restrict__ pend, float* __restrict__ sumdt) {
  int chunk = blockIdx.x, p = blockIdx.y, dir = p >> 1;
  int tid = threadIdx.x; int s = tid & 15, dg = tid >> 4;
  int d0 = dg*8;
  float A[8], ps[8], sd[8];
  #pragma unroll
  for (int i = 0; i < 8; ++i) {
    A[i] = -__expf(alog[((dir*128 + d0 + i) << 4) + s]);
    ps[i] = 0.f; sd[i] = 0.f;
  }
  long rowbase = (long)p*4096 + chunk*64;
  for (int l = 0; l < 64; ++l) {
    long t = rowbase + l;
    float4 dta = *(const float4*)(dt + t*128 + d0);
    float4 dtb = *(const float4*)(dt + t*128 + d0 + 4);
    float4 ua  = *(const float4*)(u  + t*128 + d0);
    float4 ub  = *(const float4*)(u  + t*128 + d0 + 4);
    float Bc = dbl[t*36 + 4 + s];
    float dv[8] = {dta.x,dta.y,dta.z,dta.w,dtb.x,dtb.y,dtb.z,dtb.w};
    float uv[8] = {ua.x,ua.y,ua.z,ua.w,ub.x,ub.y,ub.z,ub.w};
    #pragma unroll
    for (int i = 0; i < 8; ++i) {
      float dA = __expf(dv[i]*A[i]);
      ps[i] = dA*ps[i] + dv[i]*uv[i]*Bc;
      sd[i] += dv[i];
    }
  }
  long cb = (long)(p*64 + chunk)*128;
  #pragma unroll
  for (int i = 0; i < 8; ++i) {
    pend[(cb + d0 + i)*16 + s] = ps[i];
    if (s == 0) sumdt[cb + d0 + i] = sd[i];
  }
}

// ---------------- Scan phase 2: carry scan over 64 chunk summaries ----------------
__global__ __launch_bounds__(256) void k_scan2(const float* __restrict__ pend, const float* __restrict__ sumdt,
    const float* __restrict__ alog, float* __restrict__ carry) {
  int gid = blockIdx.x*256 + threadIdx.x;  // 16384 = 8*128*16
  int p = gid >> 11; int r = gid & 2047; int d = r >> 4; int s = r & 15; int dir = p >> 1;
  float A = -__expf(alog[((dir*128 + d) << 4) + s]);
  float c = 0.f;
  for (int ch = 0; ch < 64; ++ch) {
    long idx = (long)(p*64 + ch)*128 + d;
    carry[idx*16 + s] = c;
    c = __expf(A * sumdt[idx]) * c + pend[idx*16 + s];
  }
}

// ---------------- Scan phase 3: full recurrence from carry, fused y ----------------
__global__ __launch_bounds__(256) void k_scan3(const float* __restrict__ dt, const float* __restrict__ u,
    const float* __restrict__ dbl, const float* __restrict__ xz, const float* __restrict__ alog,
    const float* __restrict__ Dp, const float* __restrict__ carry, float* __restrict__ y) {
  int chunk = blockIdx.x, p = blockIdx.y, dir = p >> 1;
  int tid = threadIdx.x; int s = tid & 15, dg = tid >> 4;
  int d0 = dg*8;
  float A[8], h[8], Dv[8];
  long cb = (long)(p*64 + chunk)*128;
  #pragma unroll
  for (int i = 0; i < 8; ++i) {
    A[i] = -__expf(alog[((dir*128 + d0 + i) << 4) + s]);
    h[i] = carry[(cb + d0 + i)*16 + s];
    Dv[i] = Dp[dir*128 + d0 + i];
  }
  long rowbase = (long)p*4096 + chunk*64;
  for (int l = 0; l < 64; ++l) {
    long t = rowbase + l;
    float4 dta = *(const float4*)(dt + t*128 + d0);
    float4 dtb = *(const float4*)(dt + t*128 + d0 + 4);
    float4 ua  = *(const float4*)(u  + t*128 + d0);
    float4 ub  = *(const float4*)(u  + t*128 + d0 + 4);
    float4 za  = *(const float4*)(xz + t*256 + 128 + d0);
    float4 zb  = *(const float4*)(xz + t*256 + 128 + d0 + 4);
    float Bc = dbl[t*36 + 4 + s];
    float Cc = dbl[t*36 + 20 + s];
    float dv[8] = {dta.x,dta.y,dta.z,dta.w,dtb.x,dtb.y,dtb.z,dtb.w};
    float uv[8] = {ua.x,ua.y,ua.z,ua.w,ub.x,ub.y,ub.z,ub.w};
    float zv[8] = {za.x,za.y,za.z,za.w,zb.x,zb.y,zb.z,zb.w};
    float yo[8];
    #pragma unroll
    for (int i = 0; i < 8; ++i) {
      float dA = __expf(dv[i]*A[i]);
      h[i] = dA*h[i] + dv[i]*uv[i]*Bc;
      yo[i] = h[i]*Cc;
    }
    #pragma unroll
    for (int i = 0; i < 8; ++i) {
      float v = yo[i];
      v += __shfl_xor(v, 1);
      v += __shfl_xor(v, 2);
      v += __shfl_xor(v, 4);
      v += __shfl_xor(v, 8);
      yo[i] = v;
    }
    if (s == 0) {
      #pragma unroll
      for (int i = 0; i < 8; ++i) {
        float yv = yo[i] + uv[i]*Dv[i];
        float z = zv[i];
        yv *= z * sigmoidf_(z);
        y[t*128 + d0 + i] = yv;
      }
    }
  }
}

// ---------------- Combine 4 directions back to (B,C,H,W) ----------------
__global__ __launch_bounds__(256) void k_comb(const float* __restrict__ yg, float* __restrict__ out) {
  int o = blockIdx.x*256 + threadIdx.x;  // 524288
  int w = o & 63, h = (o>>6)&63, c = (o>>12)&63, b = o>>18;
  int t0 = (h<<6)|w, t2 = (w<<6)|h;
  float v = yg[((long)(b*4096) + t0)*64 + c]
          + yg[((long)((2+b)*4096) + (4095 - t0))*64 + c]
          + yg[((long)((4+b)*4096) + t2)*64 + c]
          + yg[((long)((6+b)*4096) + (4095 - t2))*64 + c];
  out[o] = v;
}

extern "C" void kernel_launch(void* const* d_in, const int* in_sizes, int n_in,
                              void* d_out, int out_size, void* d_ws, size_t ws_size,
                              hipStream_t stream) {
  const float* x      = (const float*)d_in[0];
  const float* ln_w   = (const float*)d_in[1];
  const float* ln_b   = (const float*)d_in[2];
  const float* W_in   = (const float*)d_in[3];
  const float* conv_w = (const float*)d_in[4];
  const float* conv_b = (const float*)d_in[5];
  const float* W_xp   = (const float*)d_in[6];
  const float* W_dt   = (const float*)d_in[7];
  const float* b_dt   = (const float*)d_in[8];
  const float* A_log  = (const float*)d_in[9];
  const float* D_par  = (const float*)d_in[10];
  const float* W_out  = (const float*)d_in[11];

  float* ws    = (float*)d_ws;
  float* xn    = ws;                    // 524288
  float* xseq  = xn    + 524288;        // 2097152
  float* xz    = xseq  + 2097152;       // 8388608  (xp | z)
  float* u     = xz    + 8388608;       // 4194304
  float* dblb  = u     + 4194304;       // 1179648  (dt_raw | Bc | Cc)
  float* dtb   = dblb  + 1179648;       // 4194304
  float* pend  = dtb   + 4194304;       // 1048576
  float* sumdt = pend  + 1048576;       // 65536
  float* carry = sumdt + 65536;         // 1048576
  float* ybuf  = carry + 1048576;       // 4194304
  float* yg    = ybuf  + 4194304;       // 2097152   total ~116 MB

  k_ln  <<<2048, 256, 0, stream>>>(x, ln_w, ln_b, xn);
  k_xseq<<<8192, 256, 0, stream>>>(xn, xseq);
  k_gemm<<<dim3(64,4,8), 256, 0, stream>>>(xseq, W_in, xz, 4096, 256, 64,
                                           4096L*64, 256L*64, 4096L*256);
  k_conv<<<16384, 256, 0, stream>>>(xz, conv_w, conv_b, u);
  k_gemm<<<dim3(64,1,8), 256, 0, stream>>>(u, W_xp, dblb, 4096, 36, 128,
                                           4096L*128, 36L*128, 4096L*36);
  k_dt  <<<16384, 256, 0, stream>>>(dblb, W_dt, b_dt, dtb);
  k_scan1<<<dim3(64,8), 256, 0, stream>>>(dtb, u, dblb, A_log, pend, sumdt);
  k_scan2<<<64, 256, 0, stream>>>(pend, sumdt, A_log, carry);
  k_scan3<<<dim3(64,8), 256, 0, stream>>>(dtb, u, dblb, xz, A_log, D_par, carry, ybuf);
  k_gemm<<<dim3(64,1,8), 256, 0, stream>>>(ybuf, W_out, yg, 4096, 64, 128,
                                           4096L*128, 64L*128, 4096L*64);
  k_comb<<<2048, 256, 0, stream>>>(yg, (float*)d_out);
}

// Round 2
// 245.932 us; speedup vs baseline: 1.2415x; 1.2415x over previous
//
#include <hip/hip_runtime.h>
#include <math.h>

// Mamba-2D (SS2D): B=2, C=64, H=W=64, d_inner=128, d_state=16, dt_rank=4.
// Pair p = dir*2 + b (8 pairs), L=4096. Chunked scan: CH=32, NCH=128.
// Scan layout: thread = (pair, chunk, channel d); all 16 states in registers.

#define PP  8
#define LL  4096
#define DD  128
#define SS  16
#define CH  32
#define NCH 128

__device__ __forceinline__ float sigmoidf_(float x){ return 1.0f/(1.0f+__expf(-x)); }

// ---------------- LayerNorm over channels (C=64) ----------------
__global__ __launch_bounds__(256) void k_ln(const float* __restrict__ x,
    const float* __restrict__ lw, const float* __restrict__ lb, float* __restrict__ xn) {
  int tid = threadIdx.x;
  int lane = tid & 63;                    // channel
  int pos = blockIdx.x*4 + (tid>>6);      // 0..8191 = b*4096 + hw
  int b = pos >> 12, hw = pos & 4095;
  float v = x[((long)(b*64 + lane))*4096 + hw];
  float s = v;
  for (int m = 32; m; m >>= 1) s += __shfl_xor(s, m);
  float mu = s * (1.0f/64.0f);
  float dv = (v-mu)*(v-mu);
  for (int m = 32; m; m >>= 1) dv += __shfl_xor(dv, m);
  float rs = rsqrtf(dv*(1.0f/64.0f) + 1e-5f);
  xn[(long)pos*64 + lane] = (v-mu)*rs*lw[lane] + lb[lane];
}

// ---------------- Build 4 direction-permuted sequences ----------------
__global__ __launch_bounds__(256) void k_xseq(const float* __restrict__ xn, float* __restrict__ xseq) {
  int gid = blockIdx.x*256 + threadIdx.x;   // 8*4096*64 = 2097152
  int c = gid & 63;
  int t = (gid >> 6) & 4095;
  int p = gid >> 18;
  int b = p & 1, dir = p >> 1;
  int l;
  if (dir == 0) l = t;
  else if (dir == 1) l = 4095 - t;
  else {
    int tt = (dir == 2) ? t : 4095 - t;
    l = ((tt & 63) << 6) | (tt >> 6);       // t = w*64+h  ->  l = h*64+w
  }
  xseq[gid] = xn[((long)(b*4096 + l))*64 + c];
}

// ---------------- Generic f32 GEMM: C[m,n] = sum_k A[m,k]*B[n,k] ----------------
__global__ __launch_bounds__(256) void k_gemm(const float* __restrict__ A, const float* __restrict__ Bw,
    float* __restrict__ C, int M, int N, int K, long aStr, long bStr, long cStr) {
  __shared__ float Ast[64][68];
  __shared__ float Bst[64][68];
  int pair = blockIdx.z;
  const float* Ap = A + (long)pair*aStr;
  const float* Bp = Bw + (long)(pair>>1)*bStr;
  float* Cp = C + (long)pair*cStr;
  int tid = threadIdx.x;
  int tx = tid & 15, ty = tid >> 4;
  int m0 = blockIdx.x*64, n0 = blockIdx.y*64;
  int kk4 = tid & 15, rr = tid >> 4;
  float acc[4][4] = {};
  for (int ko = 0; ko < K; ko += 64) {
    for (int pass = 0; pass < 4; ++pass) {
      int r = pass*16 + rr;
      float4 av = *(const float4*)(Ap + (long)(m0+r)*K + ko + kk4*4);
      Ast[kk4*4+0][r]=av.x; Ast[kk4*4+1][r]=av.y; Ast[kk4*4+2][r]=av.z; Ast[kk4*4+3][r]=av.w;
      int j = n0 + r;
      float4 bv = make_float4(0.f,0.f,0.f,0.f);
      if (j < N) bv = *(const float4*)(Bp + (long)j*K + ko + kk4*4);
      Bst[kk4*4+0][r]=bv.x; Bst[kk4*4+1][r]=bv.y; Bst[kk4*4+2][r]=bv.z; Bst[kk4*4+3][r]=bv.w;
    }
    __syncthreads();
    #pragma unroll 8
    for (int kk = 0; kk < 64; ++kk) {
      float4 a = *(const float4*)(&Ast[kk][ty*4]);
      float4 b = *(const float4*)(&Bst[kk][tx*4]);
      acc[0][0] += a.x*b.x; acc[0][1] += a.x*b.y; acc[0][2] += a.x*b.z; acc[0][3] += a.x*b.w;
      acc[1][0] += a.y*b.x; acc[1][1] += a.y*b.y; acc[1][2] += a.y*b.z; acc[1][3] += a.y*b.w;
      acc[2][0] += a.z*b.x; acc[2][1] += a.z*b.y; acc[2][2] += a.z*b.z; acc[2][3] += a.z*b.w;
      acc[3][0] += a.w*b.x; acc[3][1] += a.w*b.y; acc[3][2] += a.w*b.z; acc[3][3] += a.w*b.w;
    }
    __syncthreads();
  }
  for (int i = 0; i < 4; ++i)
    for (int j = 0; j < 4; ++j) {
      int m = m0 + ty*4 + i, n = n0 + tx*4 + j;
      if (n < N) Cp[(long)m*N + n] = acc[i][j];
    }
}

// ---------------- Causal depthwise conv(3) + bias + silu ----------------
__global__ __launch_bounds__(256) void k_conv(const float* __restrict__ xz, const float* __restrict__ cw,
    const float* __restrict__ cb, float* __restrict__ u) {
  int gid = blockIdx.x*256 + threadIdx.x;   // 8*4096*128
  int d = gid & 127;
  int t = (gid >> 7) & 4095;
  int p = gid >> 19;
  int dir = p >> 1;
  const float* base = xz + ((long)p*4096)*256 + d;   // xp = cols 0..127
  float x2 = base[(long)t*256];
  float x1 = (t >= 1) ? base[(long)(t-1)*256] : 0.f;
  float x0 = (t >= 2) ? base[(long)(t-2)*256] : 0.f;
  const float* w = cw + (dir*128 + d)*3;
  float a = x0*w[0] + x1*w[1] + x2*w[2] + cb[dir*128 + d];
  u[gid] = a * sigmoidf_(a);
}

// ---------------- dt = softplus(dt_raw @ W_dt^T + b_dt) ----------------
__global__ __launch_bounds__(256) void k_dt(const float* __restrict__ dbl, const float* __restrict__ wdt,
    const float* __restrict__ bdt, float* __restrict__ dt) {
  int gid = blockIdx.x*256 + threadIdx.x;   // 8*4096*128
  int d = gid & 127;
  int t = (gid >> 7) & 4095;
  int p = gid >> 19;
  int dir = p >> 1;
  const float* r = dbl + ((long)p*4096 + t)*36;
  float4 w = *(const float4*)(wdt + ((dir*128 + d) << 2));
  float lin = r[0]*w.x + r[1]*w.y + r[2]*w.z + r[3]*w.w + bdt[dir*128 + d];
  float sp = (lin > 20.f) ? lin : log1pf(__expf(lin));
  dt[gid] = sp;
}

// ---------------- Scan phase 1: per-chunk particular solution + chunk decay ----------------
// Thread = (pair, chunk, d). All 16 states in registers. Bc staged in LDS.
__global__ __launch_bounds__(128) void k_scan1(const float* __restrict__ dt, const float* __restrict__ u,
    const float* __restrict__ dbl, const float* __restrict__ alog,
    float* __restrict__ pend, float* __restrict__ dAc) {
  int ch = blockIdx.x, p = blockIdx.y, dir = p >> 1;
  int d = threadIdx.x;
  __shared__ float Bsm[CH*16];
  long rowbase = (long)p*LL + ch*CH;
  #pragma unroll
  for (int k = 0; k < 4; ++k) {
    int idx = d + k*128;                 // 0..511
    int t = idx >> 4, j = idx & 15;
    Bsm[idx] = dbl[(rowbase + t)*36 + 4 + j];
  }
  float A[16], ps[16];
  const float* ab = alog + ((dir*DD + d) << 4);
  #pragma unroll
  for (int s = 0; s < 16; ++s) { A[s] = -__expf(ab[s]); ps[s] = 0.f; }
  float sd = 0.f;
  __syncthreads();
  for (int t = 0; t < CH; ++t) {
    long row = rowbase + t;
    float dtv = dt[row*DD + d];
    float uv  = u [row*DD + d];
    float dtu = dtv*uv;
    sd += dtv;
    const float* Bs = &Bsm[t*16];
    #pragma unroll
    for (int s = 0; s < 16; ++s) {
      float dA = __expf(dtv*A[s]);
      ps[s] = fmaf(dA, ps[s], dtu*Bs[s]);
    }
  }
  long base = ((long)(p*NCH + ch)*DD + d)*16;
  #pragma unroll
  for (int s = 0; s < 16; ++s) {
    pend[base+s] = ps[s];
    dAc [base+s] = __expf(A[s]*sd);
  }
}

// ---------------- Scan phase 2: carry scan over NCH chunk summaries ----------------
__global__ __launch_bounds__(256) void k_scan2(const float* __restrict__ pend,
    const float* __restrict__ dAc, float* __restrict__ carry) {
  int g = blockIdx.x*256 + threadIdx.x;  // 16384 = 8*128*16
  long hi = ((long)(g >> 11)) << 18;     // pair * NCH*128*16
  int lo = g & 2047;                     // (d,s) within pair
  float c = 0.f;
  for (int chk = 0; chk < NCH; ++chk) {
    long idx = hi + ((long)chk << 11) + lo;
    carry[idx] = c;
    c = fmaf(dAc[idx], c, pend[idx]);
  }
}

// ---------------- Scan phase 3: full recurrence from carry, fused y/D/silu-gate ----------------
__global__ __launch_bounds__(128) void k_scan3(const float* __restrict__ dt, const float* __restrict__ u,
    const float* __restrict__ dbl, const float* __restrict__ xz, const float* __restrict__ alog,
    const float* __restrict__ Dp, const float* __restrict__ carry, float* __restrict__ y) {
  int ch = blockIdx.x, p = blockIdx.y, dir = p >> 1;
  int d = threadIdx.x;
  __shared__ float Bsm[CH*16];
  __shared__ float Csm[CH*16];
  long rowbase = (long)p*LL + ch*CH;
  #pragma unroll
  for (int k = 0; k < 8; ++k) {
    int idx = d + k*128;                 // 0..1023
    int half = idx >> 9;                 // 0: Bc, 1: Cc
    int e = idx & 511;
    int t = e >> 4, j = e & 15;
    float v = dbl[(rowbase + t)*36 + (half ? 20 : 4) + j];
    if (half) Csm[e] = v; else Bsm[e] = v;
  }
  float A[16], h[16];
  const float* ab = alog + ((dir*DD + d) << 4);
  long cbase = ((long)(p*NCH + ch)*DD + d)*16;
  #pragma unroll
  for (int s = 0; s < 16; ++s) {
    A[s] = -__expf(ab[s]);
    h[s] = carry[cbase + s];
  }
  float Dv = Dp[dir*DD + d];
  __syncthreads();
  for (int t = 0; t < CH; ++t) {
    long row = rowbase + t;
    float dtv = dt[row*DD + d];
    float uv  = u [row*DD + d];
    float zv  = xz[row*256 + 128 + d];
    float dtu = dtv*uv;
    const float* Bs = &Bsm[t*16];
    const float* Cs = &Csm[t*16];
    float acc = 0.f;
    #pragma unroll
    for (int s = 0; s < 16; ++s) {
      float dA = __expf(dtv*A[s]);
      h[s] = fmaf(dA, h[s], dtu*Bs[s]);
      acc = fmaf(h[s], Cs[s], acc);
    }
    float yv = acc + uv*Dv;
    yv *= zv * sigmoidf_(zv);
    y[row*DD + d] = yv;
  }
}

// ---------------- Combine 4 directions back to (B,C,H,W) ----------------
__global__ __launch_bounds__(256) void k_comb(const float* __restrict__ yg, float* __restrict__ out) {
  int o = blockIdx.x*256 + threadIdx.x;  // 524288
  int w = o & 63, h = (o>>6)&63, c = (o>>12)&63, b = o>>18;
  int t0 = (h<<6)|w, t2 = (w<<6)|h;
  float v = yg[((long)(b*4096) + t0)*64 + c]
          + yg[((long)((2+b)*4096) + (4095 - t0))*64 + c]
          + yg[((long)((4+b)*4096) + t2)*64 + c]
          + yg[((long)((6+b)*4096) + (4095 - t2))*64 + c];
  out[o] = v;
}

extern "C" void kernel_launch(void* const* d_in, const int* in_sizes, int n_in,
                              void* d_out, int out_size, void* d_ws, size_t ws_size,
                              hipStream_t stream) {
  const float* x      = (const float*)d_in[0];
  const float* ln_w   = (const float*)d_in[1];
  const float* ln_b   = (const float*)d_in[2];
  const float* W_in   = (const float*)d_in[3];
  const float* conv_w = (const float*)d_in[4];
  const float* conv_b = (const float*)d_in[5];
  const float* W_xp   = (const float*)d_in[6];
  const float* W_dt   = (const float*)d_in[7];
  const float* b_dt   = (const float*)d_in[8];
  const float* A_log  = (const float*)d_in[9];
  const float* D_par  = (const float*)d_in[10];
  const float* W_out  = (const float*)d_in[11];

  float* ws    = (float*)d_ws;
  float* xn    = ws;                    // 524288
  float* xseq  = xn    + 524288;        // 2097152  (reused as carry after gemm1)
  float* xz    = xseq  + 2097152;       // 8388608  (xp | z)
  float* u     = xz    + 8388608;       // 4194304
  float* dblb  = u     + 4194304;       // 1179648  (dt_raw | Bc | Cc)
  float* dtb   = dblb  + 1179648;       // 4194304
  float* ybuf  = dtb   + 4194304;       // 4194304  (first half: pend, second: dAc)
  float* yg    = ybuf  + 4194304;       // 2097152   total ~107.5 MB
  float* pend  = ybuf;                  // 2097152 (consumed by scan2 before scan3 overwrites)
  float* dAc   = ybuf  + 2097152;       // 2097152
  float* carry = xseq;                  // 2097152 (xseq dead after gemm1)

  k_ln  <<<2048, 256, 0, stream>>>(x, ln_w, ln_b, xn);
  k_xseq<<<8192, 256, 0, stream>>>(xn, xseq);
  k_gemm<<<dim3(64,4,8), 256, 0, stream>>>(xseq, W_in, xz, 4096, 256, 64,
                                           4096L*64, 256L*64, 4096L*256);
  k_conv<<<16384, 256, 0, stream>>>(xz, conv_w, conv_b, u);
  k_gemm<<<dim3(64,1,8), 256, 0, stream>>>(u, W_xp, dblb, 4096, 36, 128,
                                           4096L*128, 36L*128, 4096L*36);
  k_dt  <<<16384, 256, 0, stream>>>(dblb, W_dt, b_dt, dtb);
  k_scan1<<<dim3(NCH,PP), 128, 0, stream>>>(dtb, u, dblb, A_log, pend, dAc);
  k_scan2<<<64, 256, 0, stream>>>(pend, dAc, carry);
  k_scan3<<<dim3(NCH,PP), 128, 0, stream>>>(dtb, u, dblb, xz, A_log, D_par, carry, ybuf);
  k_gemm<<<dim3(64,1,8), 256, 0, stream>>>(ybuf, W_out, yg, 4096, 64, 128,
                                           4096L*128, 64L*128, 4096L*64);
  k_comb<<<2048, 256, 0, stream>>>(yg, (float*)d_out);
}